// Round 5
// baseline (224.496 us; speedup 1.0000x reference)
//
#include <hip/hip_runtime.h>

typedef _Float16 f16;
typedef _Float16 f16x8 __attribute__((ext_vector_type(8)));
typedef _Float16 f16x4 __attribute__((ext_vector_type(4)));
typedef _Float16 f16x2 __attribute__((ext_vector_type(2)));
typedef float f32x4 __attribute__((ext_vector_type(4)));

#define L2E 1.44269504088896f

typedef __attribute__((address_space(1))) void GV;
typedef __attribute__((address_space(3))) void LV;
__device__ __forceinline__ void gl2lds(const void* gp, void* lp) {
    __builtin_amdgcn_global_load_lds((GV*)gp, (LV*)lp, 16, 0, 0);
}

// ---------------- W convert fp32 -> f16 ----------------
__global__ void k_wcvt(const float* __restrict__ w, f16* __restrict__ wh) {
    int i = (blockIdx.x * 256 + threadIdx.x) * 4;
    float4 v = *(const float4*)(w + i);
    f16x4 o = { (f16)v.x, (f16)v.y, (f16)v.z, (f16)v.w };
    *(f16x4*)(wh + i) = o;
}

// ------- depthwise 3x3 conv + transpose [B,C,N]->[B,N,C] + f16 cast -------
__launch_bounds__(256)
__global__ void k_prep(const float* __restrict__ x, const float* __restrict__ wdw,
                       const float* __restrict__ bdw,
                       f16* __restrict__ xt, f16* __restrict__ rbt) {
    int ht = blockIdx.x, ct = blockIdx.y, b = blockIdx.z;
    __shared__ float xs[64 * 129];
    int t = threadIdx.x;
    int h0 = ht * 2;
#pragma unroll
    for (int i = 0; i < 8; ++i) {
        int idx = t + i * 256;
        int cl = idx >> 5, col4 = idx & 31;
        int hh = h0 - 1 + (col4 >> 3);
        int wq = (col4 & 7) * 4;
        float4 v = make_float4(0.f, 0.f, 0.f, 0.f);
        if (hh >= 0 && hh < 32)
            v = *(const float4*)(x + (size_t)(b * 384 + ct * 64 + cl) * 1024 + hh * 32 + wq);
        int base = cl * 129 + col4 * 4;
        xs[base] = v.x; xs[base + 1] = v.y; xs[base + 2] = v.z; xs[base + 3] = v.w;
    }
    __syncthreads();
    int cl = t & 63;
    int c = ct * 64 + cl;
    float wd[9];
#pragma unroll
    for (int k = 0; k < 9; ++k) wd[k] = wdw[c * 9 + k];
    float bd = bdw[c];
    const float* row = &xs[cl * 129];
    int nb = (t >> 6) * 16;
#pragma unroll
    for (int i = 0; i < 16; ++i) {
        int nl = nb + i;
        int hh = nl >> 5, ww = nl & 31;
        int lx = hh + 1;
        float acc = bd;
#pragma unroll
        for (int dh = -1; dh <= 1; ++dh) {
#pragma unroll
            for (int dw = -1; dw <= 1; ++dw) {
                int w2 = ww + dw;
                if (w2 >= 0 && w2 <= 31)
                    acc += wd[(dh + 1) * 3 + (dw + 1)] * row[(lx + dh) * 32 + w2];
            }
        }
        float xc = row[lx * 32 + ww];
        size_t at = ((size_t)(b * 1024) + h0 * 32 + nl) * 384 + c;
        rbt[at] = (f16)acc;
        xt[at] = (f16)xc;
    }
}

// ---------------- QKV GEMM (unchanged, known-good) ----------------
__launch_bounds__(256, 2)
__global__ void k_gemm1(const f16* __restrict__ xt, const f16* __restrict__ wh,
                        const float* __restrict__ bias, const f16* __restrict__ rbt,
                        f16* __restrict__ qo, f16* __restrict__ krb, f16* __restrict__ vt) {
    __shared__ f16 As[128 * 64];
    __shared__ f16 Bs[128 * 64];
    int bm = blockIdx.x, bn = blockIdx.y, b = blockIdx.z;
    int t = threadIdx.x, lane = t & 63, wv = t >> 6;
    int wm = wv >> 1, wn = wv & 1;
    f32x4 acc[4][4] = {};
    const char* xbase = (const char*)(xt + (size_t)(b * 1024 + bm * 128) * 384);
    const char* wbase = (const char*)(wh + (size_t)(bn * 128) * 384);
    const bool vmode = (bn >= 6);
    int soff[4];
#pragma unroll
    for (int i = 0; i < 4; ++i) {
        int idx = i * 256 + t;
        int r = idx >> 3, cg = idx & 7;
        soff[i] = r * 768 + ((cg ^ (r & 7)) << 4);
    }
    for (int kc = 0; kc < 6; ++kc) {
        __syncthreads();
#pragma unroll
        for (int i = 0; i < 4; ++i) {
            gl2lds(xbase + kc * 128 + soff[i], (char*)As + (i * 256 + wv * 64) * 16);
            gl2lds(wbase + kc * 128 + soff[i], (char*)Bs + (i * 256 + wv * 64) * 16);
        }
        __syncthreads();
#pragma unroll
        for (int j = 0; j < 2; ++j) {
            f16x8 af[4], bf[4];
#pragma unroll
            for (int mr = 0; mr < 4; ++mr) {
                int rowi = wm * 64 + mr * 16 + (lane & 15);
                af[mr] = *(const f16x8*)((const char*)As + rowi * 128 +
                         ((j * 64 + (lane >> 4) * 16) ^ ((rowi & 7) << 4)));
            }
#pragma unroll
            for (int nr = 0; nr < 4; ++nr) {
                int rowi = wn * 64 + nr * 16 + (lane & 15);
                bf[nr] = *(const f16x8*)((const char*)Bs + rowi * 128 +
                         ((j * 64 + (lane >> 4) * 16) ^ ((rowi & 7) << 4)));
            }
            __builtin_amdgcn_s_setprio(1);
            if (!vmode) {
#pragma unroll
                for (int mr = 0; mr < 4; ++mr)
#pragma unroll
                    for (int nr = 0; nr < 4; ++nr)
                        acc[mr][nr] = __builtin_amdgcn_mfma_f32_16x16x32_f16(af[mr], bf[nr], acc[mr][nr], 0, 0, 0);
            } else {
#pragma unroll
                for (int mr = 0; mr < 4; ++mr)
#pragma unroll
                    for (int nr = 0; nr < 4; ++nr)
                        acc[mr][nr] = __builtin_amdgcn_mfma_f32_16x16x32_f16(bf[nr], af[mr], acc[mr][nr], 0, 0, 0);
            }
            __builtin_amdgcn_s_setprio(0);
        }
    }
    int o0 = bn * 128;
    if (!vmode) {
#pragma unroll
        for (int nr = 0; nr < 4; ++nr) {
            int o = o0 + wn * 64 + nr * 16 + (lane & 15);
            float bs = bias[o];
#pragma unroll
            for (int mr = 0; mr < 4; ++mr) {
                int n_l = wm * 64 + mr * 16 + ((lane >> 4) << 2);
#pragma unroll
                for (int r = 0; r < 4; ++r) {
                    int n_sp = bm * 128 + n_l + r;
                    size_t at = (size_t)(b * 1024 + n_sp) * 384;
                    float vv = acc[mr][nr][r] + bs;
                    if (o < 384) qo[at + o] = (f16)vv;
                    else krb[at + (o - 384)] = (f16)(vv + (float)rbt[at + (o - 384)]);
                }
            }
        }
    } else {
#pragma unroll
        for (int nr = 0; nr < 4; ++nr) {
#pragma unroll
            for (int mr = 0; mr < 4; ++mr) {
                int n_sp = bm * 128 + wm * 64 + mr * 16 + (lane & 15);
                int o_l = wn * 64 + nr * 16 + ((lane >> 4) << 2);
#pragma unroll
                for (int r = 0; r < 4; ++r) {
                    float vv = acc[mr][nr][r] + bias[o0 + o_l + r];
                    vt[(size_t)(b * 384 + (o0 - 768) + o_l + r) * 1024 + n_sp] = (f16)vv;
                }
            }
        }
    }
}

// ---------------- flash attention v4: QBLK=32, in-block split-KV, 2 blocks/CU ----------------
// grid: (qt=32, b=16), 256 threads (4 waves). Wave pair h in {0,1} handles kv half h.
// Wave (2h+qw) owns q-rows qt*32 + qw*16 .. +15. KVBLK=16.
// LDS: KsA,KsB [16][768B] (12KB each) + VsA,VsB [384][32B] (12KB each) = 48KB + ml.
__launch_bounds__(256, 2)
__global__ void k_flash4(const f16* __restrict__ q, const f16* __restrict__ krb,
                         const f16* __restrict__ vt, float* __restrict__ out) {
    __shared__ char smem[49152];
    __shared__ float mlb[32][2];
    int qt = blockIdx.x, b = blockIdx.y;
    int t = threadIdx.x, lane = t & 63, wv = t >> 6;
    int g = lane >> 4, ln = lane & 15;
    int h = wv >> 1, qw = wv & 1;
    char* Ks = smem + h * 12288;
    char* Vs = smem + 24576 + h * 12288;

    // Q as B-fragment of QK (col=q=ln, k=g*8+e per 32-c chunk)
    f16x8 qf[12];
    {
        const f16* qb = q + (size_t)(b * 1024 + qt * 32 + qw * 16 + ln) * 384 + g * 8;
#pragma unroll
        for (int kc = 0; kc < 12; ++kc) qf[kc] = *(const f16x8*)(qb + kc * 32);
    }

    // staging offsets (pre-swizzled global source; linear LDS dest). 768 granules/half.
    int tp = t & 127;
    int koff[6], voff[6];
#pragma unroll
    for (int i = 0; i < 6; ++i) {
        int idx = i * 128 + tp;
        int r = idx / 48, c = idx - r * 48;            // K: 16 rows x 48 granules
        koff[i] = r * 768 + ((c ^ (r & 7)) << 4);
        int vr = idx >> 1, vc = idx & 1;               // V: 384 rows x 2 granules
        voff[i] = vr * 2048 + ((vc ^ ((vr >> 2) & 1)) << 4);
    }
    const char* kbase = (const char*)krb + (size_t)b * 786432 + (size_t)(h * 512) * 768;
    const char* vbase = (const char*)vt + (size_t)b * 786432 + (size_t)(h * 512) * 2;

    // prologue: stage K[0]
#pragma unroll
    for (int i = 0; i < 6; ++i)
        gl2lds(kbase + koff[i], Ks + (i * 128 + qw * 64) * 16);

    f32x4 oa[24];
#pragma unroll
    for (int i = 0; i < 24; ++i) oa[i] = (f32x4){0.f, 0.f, 0.f, 0.f};
    float m_run = -1e30f, l_run = 0.f;

    for (int kt = 0; kt < 32; ++kt) {
        __syncthreads();               // K[kt] landed; Vs free
#pragma unroll
        for (int i = 0; i < 6; ++i)    // async stage V[kt] under QK
            gl2lds(vbase + kt * 32 + voff[i], Vs + (i * 128 + qw * 64) * 16);

        // QK^T swapped: S^T[kv][q], kv = g*4+r (local), q = ln
        f32x4 st = {};
        __builtin_amdgcn_s_setprio(1);
#pragma unroll
        for (int kc = 0; kc < 12; ++kc) {
            f16x8 kf = *(const f16x8*)(Ks + ln * 768 +
                        ((kc * 64 + g * 16) ^ ((ln & 7) << 4)));
            st = __builtin_amdgcn_mfma_f32_16x16x32_f16(kf, qf[kc], st, 0, 0, 0);
        }
        __builtin_amdgcn_s_setprio(0);

        // register online softmax, T13 defer-rescale
        float mx = fmaxf(fmaxf(st[0], st[1]), fmaxf(st[2], st[3]));
        mx = fmaxf(mx, __shfl_xor(mx, 16));
        mx = fmaxf(mx, __shfl_xor(mx, 32));
        float mn;
        if (__all(mx <= m_run + 8.0f)) {
            mn = m_run;                // defer: P bounded by e^8, no O-rescale
        } else {
            mn = fmaxf(m_run, mx);
            float sc = exp2f((m_run - mn) * L2E);
            m_run = mn;
            l_run *= sc;
#pragma unroll
            for (int i = 0; i < 24; ++i) oa[i] *= sc;
        }
        float p[4], ls = 0.f;
#pragma unroll
        for (int r = 0; r < 4; ++r) {
            p[r] = exp2f((st[r] - mn) * L2E);
            ls += p[r];
        }
        ls += __shfl_xor(ls, 16);
        ls += __shfl_xor(ls, 32);
        l_run += ls;
        // P fragment for K=16 PV is exactly the QK output layout: no shuffle
        f16x4 pb = { (f16)p[0], (f16)p[1], (f16)p[2], (f16)p[3] };

        __syncthreads();               // V[kt] landed; Ks consumed
        if (kt < 31) {                 // async stage K[kt+1] under PV
#pragma unroll
            for (int i = 0; i < 6; ++i)
                gl2lds(kbase + (kt + 1) * 12288 + koff[i], Ks + (i * 128 + qw * 64) * 16);
        }

        // PV: O^T[c][q] += V^T x P^T  (16x16x16, b64 V reads, 2-way conflict-free)
        __builtin_amdgcn_s_setprio(1);
#pragma unroll
        for (int nr2 = 0; nr2 < 24; ++nr2) {
            int c = nr2 * 16 + ln;
            f16x4 vf = *(const f16x4*)(Vs + c * 32 +
                        ((g ^ (((c >> 2) & 1) << 1)) << 3));
            oa[nr2] = __builtin_amdgcn_mfma_f32_16x16x16f16(vf, pb, oa[nr2], 0, 0, 0);
        }
        __builtin_amdgcn_s_setprio(0);
    }

    // ---- combine halves via LDS, then store out[b][c][n] ----
    __syncthreads();                   // staging buffers free for reuse
    float* ob = (float*)smem;          // [384 c][32 q] f32 = 48KB
    if (h == 1) {
        if (g == 0) {
            mlb[qw * 16 + ln][0] = m_run;
            mlb[qw * 16 + ln][1] = l_run;
        }
#pragma unroll
        for (int nr2 = 0; nr2 < 24; ++nr2)
#pragma unroll
            for (int r = 0; r < 4; ++r)
                ob[(nr2 * 16 + g * 4 + r) * 32 + qw * 16 + ln] = oa[nr2][r];
    }
    __syncthreads();
    if (h == 0) {
        int qq = qw * 16 + ln;
        float mB = mlb[qq][0], lB = mlb[qq][1];
        float M = fmaxf(m_run, mB);
        float eA = exp2f((m_run - M) * L2E);
        float eB = exp2f((mB - M) * L2E);
        float linv = 1.0f / (l_run * eA + lB * eB);
#pragma unroll
        for (int nr2 = 0; nr2 < 24; ++nr2) {
#pragma unroll
            for (int r = 0; r < 4; ++r) {
                int c = nr2 * 16 + g * 4 + r;
                out[(size_t)(b * 384 + c) * 1024 + qt * 32 + qq] =
                    (oa[nr2][r] * eA + ob[c * 32 + qq] * eB) * linv;
            }
        }
    }
}

extern "C" void kernel_launch(void* const* d_in, const int* in_sizes, int n_in,
                              void* d_out, int out_size, void* d_ws, size_t ws_size,
                              hipStream_t stream) {
    const float* x     = (const float*)d_in[0];
    const float* w_qkv = (const float*)d_in[1];
    const float* b_qkv = (const float*)d_in[2];
    const float* w_dw  = (const float*)d_in[3];
    const float* b_dw  = (const float*)d_in[4];
    float* out = (float*)d_out;
    char* ws = (char*)d_ws;
    const size_t SZ = (size_t)16 * 1024 * 384 * 2;
    f16* xt  = (f16*)(ws);
    f16* rbt = (f16*)(ws + SZ);
    f16* qo  = (f16*)(ws + 2 * SZ);
    f16* krb = (f16*)(ws + 3 * SZ);
    f16* vt  = (f16*)(ws + 4 * SZ);
    f16* wh  = (f16*)(ws + 5 * SZ);

    k_wcvt<<<432, 256, 0, stream>>>(w_qkv, wh);
    k_prep<<<dim3(16, 6, 16), 256, 0, stream>>>(x, w_dw, b_dw, xt, rbt);
    k_gemm1<<<dim3(8, 9, 16), 256, 0, stream>>>(xt, wh, b_qkv, rbt, qo, krb, vt);
    k_flash4<<<dim3(32, 16), 256, 0, stream>>>(qo, krb, vt, out);
}